// Round 1
// baseline (115.776 us; speedup 1.0000x reference)
//
#include <hip/hip_runtime.h>

#define D_MODEL 256
#define N_HEADS 8
#define MAXN 128    // max neighbors/row; Poisson(32): P(row>128) ~ 1e-40
#define NGEMM 384   // 3 z * 32 by * 4 bx

typedef __attribute__((ext_vector_type(8))) short bf16x8;
typedef __attribute__((ext_vector_type(4))) float f32x4;

__device__ __forceinline__ unsigned short f2bf(float f) {
    union { float f; unsigned int u; } v; v.f = f;
    unsigned int r = v.u + 0x7fff + ((v.u >> 16) & 1);   // RNE
    return (unsigned short)(r >> 16);
}
__device__ __forceinline__ float bf2f(unsigned short u) {
    union { unsigned int u; float f; } v; v.u = ((unsigned int)u) << 16;
    return v.f;
}

// ---------------------------------------------------------------------------
// prep: fp32->bf16 converts (x + 4 weights) AND mask init (zeros + diagonal).
// ---------------------------------------------------------------------------
__global__ void prep_kernel(const float* __restrict__ x,
                            const float* __restrict__ W0, const float* __restrict__ W1,
                            const float* __restrict__ W2, const float* __restrict__ W3,
                            unsigned short* __restrict__ xb,
                            unsigned short* __restrict__ O0, unsigned short* __restrict__ O1,
                            unsigned short* __restrict__ O2, unsigned short* __restrict__ O3,
                            unsigned long long* __restrict__ mask, int n) {
    const int XV = (4096 * 256) / 4;          // 262144 float4s of x
    int i = blockIdx.x * blockDim.x + threadIdx.x;

    int wpr = n >> 6;
    int mwords = n * wpr;
    if (i < mwords) {
        int row = i >> 6;                     // wpr == 64
        int w = i & 63;
        mask[i] = (w == (row >> 6)) ? (1ULL << (row & 63)) : 0ULL;
    }

    const float* src;
    unsigned short* dst;
    int k;
    if (i < XV) {
        src = x; dst = xb; k = i;
    } else {
        int i2 = i - XV;                      // < 4*16384
        if (i2 >= 4 * 16384) return;
        int z = i2 >> 14;
        k = i2 & 16383;
        src = (z == 0) ? W0 : (z == 1) ? W1 : (z == 2) ? W2 : W3;
        dst = (z == 0) ? O0 : (z == 1) ? O1 : (z == 2) ? O2 : O3;
    }
    float4 v = *(const float4*)(src + (size_t)k * 4);
    ushort4 o;
    o.x = f2bf(v.x); o.y = f2bf(v.y); o.z = f2bf(v.z); o.w = f2bf(v.w);
    *(ushort4*)(dst + (size_t)k * 4) = o;
}

// ---------------------------------------------------------------------------
// Fused: QKV GEMM (blocks 0..NGEMM-1) + edge-mask atomicOr (blocks NGEMM..).
// GEMM: C = xb @ W^T (bf16 in, bf16 out). BM=128, BN=64, BK=64.
// 28 KB LDS -> 4 blocks/CU (BK=128 variant measured worse: 52 KB -> 2-3/CU).
// ---------------------------------------------------------------------------
__global__ __launch_bounds__(256) void qkv_edges_kernel(
        const unsigned short* __restrict__ xb,
        const unsigned short* __restrict__ Wq, const unsigned short* __restrict__ Wk,
        const unsigned short* __restrict__ Wv,
        unsigned short* __restrict__ Qb, unsigned short* __restrict__ Kb,
        unsigned short* __restrict__ Vb,
        const int* __restrict__ ei, unsigned long long* __restrict__ mask,
        int E, int n) {
    int blk = blockIdx.x;
    if (blk >= NGEMM) {
        int e = (blk - NGEMM) * 256 + threadIdx.x;
        if (e < E) {
            int src = ei[e];
            int dst = ei[E + e];
            int wpr = n >> 6;
            atomicOr(&mask[(size_t)dst * wpr + (src >> 6)], 1ULL << (src & 63));
        }
        return;
    }
    int z = blk >> 7;
    int r = blk & 127;
    int by = r >> 2, bx = r & 3;
    const unsigned short* B = (z == 0) ? Wq : (z == 1) ? Wk : Wv;
    unsigned short* Cb = (z == 0) ? Qb : (z == 1) ? Kb : Vb;

    __shared__ short Alds[128][72];   // +8 pad
    __shared__ short Blds[64][72];
    int t = threadIdx.x;
    int wave = t >> 6, lane = t & 63;
    int wr = wave >> 1, wc = wave & 1;
    int lr = t >> 3;
    int lk = (t & 7) << 3;

    const unsigned short* Abase = xb + ((size_t)(by * 128 + lr)) * D_MODEL + lk;
    const unsigned short* Bbase = B + ((size_t)(bx * 64 + lr)) * D_MODEL + lk;

    int fm = lane & 15;
    int fk = (lane >> 4) << 3;

    f32x4 acc[4][2];
#pragma unroll
    for (int rr = 0; rr < 4; ++rr)
#pragma unroll
        for (int c = 0; c < 2; ++c) acc[rr][c] = (f32x4){0.f, 0.f, 0.f, 0.f};

    for (int k0 = 0; k0 < D_MODEL; k0 += 64) {
        *(uint4*)&Alds[lr][lk]      = *(const uint4*)(Abase + k0);
        *(uint4*)&Alds[lr + 32][lk] = *(const uint4*)(Abase + 32 * D_MODEL + k0);
        *(uint4*)&Alds[lr + 64][lk] = *(const uint4*)(Abase + 64 * D_MODEL + k0);
        *(uint4*)&Alds[lr + 96][lk] = *(const uint4*)(Abase + 96 * D_MODEL + k0);
        *(uint4*)&Blds[lr][lk]      = *(const uint4*)(Bbase + k0);
        *(uint4*)&Blds[lr + 32][lk] = *(const uint4*)(Bbase + 32 * D_MODEL + k0);
        __syncthreads();
#pragma unroll
        for (int ks = 0; ks < 64; ks += 32) {
            bf16x8 af[4], bf[2];
#pragma unroll
            for (int rr = 0; rr < 4; ++rr)
                af[rr] = *(const bf16x8*)&Alds[wr * 64 + rr * 16 + fm][ks + fk];
#pragma unroll
            for (int c = 0; c < 2; ++c)
                bf[c] = *(const bf16x8*)&Blds[wc * 32 + c * 16 + fm][ks + fk];
#pragma unroll
            for (int rr = 0; rr < 4; ++rr)
#pragma unroll
                for (int c = 0; c < 2; ++c)
                    acc[rr][c] = __builtin_amdgcn_mfma_f32_16x16x32_bf16(
                        af[rr], bf[c], acc[rr][c], 0, 0, 0);
        }
        __syncthreads();
    }

    int orow0 = by * 128 + wr * 64 + ((lane >> 4) << 2);
    int ocol0 = bx * 64 + wc * 32 + (lane & 15);
#pragma unroll
    for (int rr = 0; rr < 4; ++rr)
#pragma unroll
        for (int c = 0; c < 2; ++c)
#pragma unroll
            for (int q = 0; q < 4; ++q)
                Cb[(size_t)(orow0 + rr * 16 + q) * D_MODEL + ocol0 + c * 16] =
                    f2bf(acc[rr][c][q]);
}

// ---------------------------------------------------------------------------
// Sparse attention, SINGLE-PASS online-softmax, register-resident pipeline.
// One wave per dst. Per 16-neighbor tile:
//   - issue all 16 V uint2 gathers up front (latency hides under MFMA+softmax)
//   - K tile double-buffered in regs: prefetch t+1 while computing t
//   - softmax entirely via wave shfl: NO LDS ops, NO barriers in the loop
//     -> compiler emits exact counted vmcnt waits; prefetches stay in flight.
// (R0 theory: old 2-pass version was gather-latency-bound: ~10 serial
//  LDS->gather round trips per wave at 4 waves/SIMD occupancy.)
// ---------------------------------------------------------------------------
#define LOAD_K(KR, tt)                                                        \
    do {                                                                      \
        int _ti = (tt);                                                       \
        if (_ti < nt) {                                                       \
            int _ix = nbr[_ti * 16 + col];                                    \
            const unsigned short* _kr = Kb + _ix * D_MODEL + (kq << 3);       \
            KR[0] = *(const bf16x8*)(_kr + 0 * 32);                           \
            KR[1] = *(const bf16x8*)(_kr + 1 * 32);                           \
            KR[2] = *(const bf16x8*)(_kr + 2 * 32);                           \
            KR[3] = *(const bf16x8*)(_kr + 3 * 32);                           \
            KR[4] = *(const bf16x8*)(_kr + 4 * 32);                           \
            KR[5] = *(const bf16x8*)(_kr + 5 * 32);                           \
            KR[6] = *(const bf16x8*)(_kr + 6 * 32);                           \
            KR[7] = *(const bf16x8*)(_kr + 7 * 32);                           \
        }                                                                     \
    } while (0)

#define FMA4(P, W, V)                                                         \
    do {                                                                      \
        P[0] += (W) * bf2f((unsigned short)((V).x & 0xffff));                 \
        P[1] += (W) * bf2f((unsigned short)((V).x >> 16));                    \
        P[2] += (W) * bf2f((unsigned short)((V).y & 0xffff));                 \
        P[3] += (W) * bf2f((unsigned short)((V).y >> 16));                    \
    } while (0)

#define TILE_BODY(KC, KN, tt)                                                 \
    do {                                                                      \
        int _t = (tt);                                                        \
        int _b0 = _t << 4;                                                    \
        /* neighbor ids (broadcast LDS reads, 16B) */                         \
        int4 _i0 = *(const int4*)&nbr[_b0];                                   \
        int4 _i1 = *(const int4*)&nbr[_b0 + 4];                               \
        int4 _i2 = *(const int4*)&nbr[_b0 + 8];                               \
        int4 _i3 = *(const int4*)&nbr[_b0 + 12];                              \
        /* issue all V gathers for this tile NOW (consumed after softmax) */  \
        uint2 _v0  = *(const uint2*)(vbase + _i0.x * D_MODEL);                \
        uint2 _v1  = *(const uint2*)(vbase + _i0.y * D_MODEL);                \
        uint2 _v2  = *(const uint2*)(vbase + _i0.z * D_MODEL);                \
        uint2 _v3  = *(const uint2*)(vbase + _i0.w * D_MODEL);                \
        uint2 _v4  = *(const uint2*)(vbase + _i1.x * D_MODEL);                \
        uint2 _v5  = *(const uint2*)(vbase + _i1.y * D_MODEL);                \
        uint2 _v6  = *(const uint2*)(vbase + _i1.z * D_MODEL);                \
        uint2 _v7  = *(const uint2*)(vbase + _i1.w * D_MODEL);                \
        uint2 _v8  = *(const uint2*)(vbase + _i2.x * D_MODEL);                \
        uint2 _v9  = *(const uint2*)(vbase + _i2.y * D_MODEL);                \
        uint2 _v10 = *(const uint2*)(vbase + _i2.z * D_MODEL);                \
        uint2 _v11 = *(const uint2*)(vbase + _i2.w * D_MODEL);                \
        uint2 _v12 = *(const uint2*)(vbase + _i3.x * D_MODEL);                \
        uint2 _v13 = *(const uint2*)(vbase + _i3.y * D_MODEL);                \
        uint2 _v14 = *(const uint2*)(vbase + _i3.z * D_MODEL);                \
        uint2 _v15 = *(const uint2*)(vbase + _i3.w * D_MODEL);                \
        /* prefetch next K tile (consumed next iteration) */                  \
        LOAD_K(KN, _t + 1);                                                   \
        /* scores via MFMA (head-masked B trick, unchanged layout) */         \
        f32x4 _c0 = (f32x4){0.f, 0.f, 0.f, 0.f};                              \
        f32x4 _c1 = (f32x4){0.f, 0.f, 0.f, 0.f};                              \
        _c0 = __builtin_amdgcn_mfma_f32_16x16x32_bf16(KC[0], (col == 0) ? qf : zf, _c0, 0, 0, 0); \
        _c1 = __builtin_amdgcn_mfma_f32_16x16x32_bf16(KC[1], (col == 1) ? qf : zf, _c1, 0, 0, 0); \
        _c0 = __builtin_amdgcn_mfma_f32_16x16x32_bf16(KC[2], (col == 2) ? qf : zf, _c0, 0, 0, 0); \
        _c1 = __builtin_amdgcn_mfma_f32_16x16x32_bf16(KC[3], (col == 3) ? qf : zf, _c1, 0, 0, 0); \
        _c0 = __builtin_amdgcn_mfma_f32_16x16x32_bf16(KC[4], (col == 4) ? qf : zf, _c0, 0, 0, 0); \
        _c1 = __builtin_amdgcn_mfma_f32_16x16x32_bf16(KC[5], (col == 5) ? qf : zf, _c1, 0, 0, 0); \
        _c0 = __builtin_amdgcn_mfma_f32_16x16x32_bf16(KC[6], (col == 6) ? qf : zf, _c0, 0, 0, 0); \
        _c1 = __builtin_amdgcn_mfma_f32_16x16x32_bf16(KC[7], (col == 7) ? qf : zf, _c1, 0, 0, 0); \
        float _s0 = (_c0[0] + _c1[0]) * inv_scale;                            \
        float _s1 = (_c0[1] + _c1[1]) * inv_scale;                            \
        float _s2 = (_c0[2] + _c1[2]) * inv_scale;                            \
        float _s3 = (_c0[3] + _c1[3]) * inv_scale;                            \
        int _jr = _b0 + (kq << 2);                                            \
        _s0 = (_jr + 0 < cnt) ? _s0 : -1e30f;                                 \
        _s1 = (_jr + 1 < cnt) ? _s1 : -1e30f;                                 \
        _s2 = (_jr + 2 < cnt) ? _s2 : -1e30f;                                 \
        _s3 = (_jr + 3 < cnt) ? _s3 : -1e30f;                                 \
        /* tile max + sum per head (reduce over the 4 kq lanes of this col) */\
        float _mt = fmaxf(fmaxf(_s0, _s1), fmaxf(_s2, _s3));                  \
        _mt = fmaxf(_mt, __shfl_xor(_mt, 16, 64));                            \
        _mt = fmaxf(_mt, __shfl_xor(_mt, 32, 64));                            \
        float _w0 = __expf(_s0 - _mt);                                        \
        float _w1 = __expf(_s1 - _mt);                                        \
        float _w2 = __expf(_s2 - _mt);                                        \
        float _w3 = __expf(_s3 - _mt);                                        \
        float _ts = (_w0 + _w1) + (_w2 + _w3);                                \
        _ts += __shfl_xor(_ts, 16, 64);                                       \
        _ts += __shfl_xor(_ts, 32, 64);                                       \
        /* online-softmax update on PV lanes (head h = L>>3) */               \
        float _mh = __shfl(_mt, h, 64);                                       \
        float _th = __shfl(_ts, h, 64);                                       \
        float _mn = fmaxf(m, _mh);                                            \
        float _so = __expf(m - _mn);                                          \
        float _f  = __expf(_mh - _mn);                                        \
        m = _mn;                                                              \
        l = l * _so + _th * _f;                                               \
        /* PV: pull the 16 tile weights of head h via shfl, FMA with V */     \
        f32x4 _p = (f32x4){0.f, 0.f, 0.f, 0.f};                               \
        {                                                                     \
            float _wa = __shfl(_w0, h, 64), _wb = __shfl(_w1, h, 64);         \
            float _wc = __shfl(_w2, h, 64), _wd = __shfl(_w3, h, 64);         \
            FMA4(_p, _wa, _v0); FMA4(_p, _wb, _v1);                           \
            FMA4(_p, _wc, _v2); FMA4(_p, _wd, _v3);                           \
        }                                                                     \
        {                                                                     \
            float _wa = __shfl(_w0, h + 16, 64), _wb = __shfl(_w1, h + 16, 64); \
            float _wc = __shfl(_w2, h + 16, 64), _wd = __shfl(_w3, h + 16, 64); \
            FMA4(_p, _wa, _v4); FMA4(_p, _wb, _v5);                           \
            FMA4(_p, _wc, _v6); FMA4(_p, _wd, _v7);                           \
        }                                                                     \
        {                                                                     \
            float _wa = __shfl(_w0, h + 32, 64), _wb = __shfl(_w1, h + 32, 64); \
            float _wc = __shfl(_w2, h + 32, 64), _wd = __shfl(_w3, h + 32, 64); \
            FMA4(_p, _wa, _v8); FMA4(_p, _wb, _v9);                           \
            FMA4(_p, _wc, _v10); FMA4(_p, _wd, _v11);                         \
        }                                                                     \
        {                                                                     \
            float _wa = __shfl(_w0, h + 48, 64), _wb = __shfl(_w1, h + 48, 64); \
            float _wc = __shfl(_w2, h + 48, 64), _wd = __shfl(_w3, h + 48, 64); \
            FMA4(_p, _wa, _v12); FMA4(_p, _wb, _v13);                         \
            FMA4(_p, _wc, _v14); FMA4(_p, _wd, _v15);                         \
        }                                                                     \
        acc[0] = acc[0] * _so + _p[0] * _f;                                   \
        acc[1] = acc[1] * _so + _p[1] * _f;                                   \
        acc[2] = acc[2] * _so + _p[2] * _f;                                   \
        acc[3] = acc[3] * _so + _p[3] * _f;                                   \
    } while (0)

__global__ __launch_bounds__(64) void attn_kernel(
        const unsigned short* __restrict__ Qb, const unsigned short* __restrict__ Kb,
        const unsigned short* __restrict__ Vb,
        const unsigned long long* __restrict__ mask,
        unsigned short* __restrict__ Ob, int n) {
    int dst = blockIdx.x;
    int L = threadIdx.x;
    int wpr = n >> 6;

    __shared__ alignas(16) int nbr[MAXN + 16];

    // ---- Phase A: neighbor enumeration ----
    unsigned long long w = (L < wpr) ? mask[(size_t)dst * wpr + L] : 0ULL;
    int c = __popcll(w);
    int xs = c;
#pragma unroll
    for (int o = 1; o < 64; o <<= 1) {
        int y = __shfl_up(xs, o, 64);
        if (L >= o) xs += y;
    }
    int pos = xs - c;
    while (w) {
        int b = __builtin_ctzll(w);
        w &= w - 1;
        if (pos < MAXN) nbr[pos] = (L << 6) + b;
        ++pos;
    }
    int cnt = __shfl(xs, 63, 64);
    if (cnt > MAXN) cnt = MAXN;
    int nb = (cnt + 15) & ~15;
    __syncthreads();
    int last = nbr[cnt - 1];
    if (L < nb - cnt) nbr[cnt + L] = last;   // pad; padded scores forced to -1e30
    __syncthreads();
    int nt = nb >> 4;

    // score-lane config (col = neighbor slot / head column, kq = k-quarter)
    int col = L & 15;
    int kq = L >> 4;
    bf16x8 qf = (bf16x8){0, 0, 0, 0, 0, 0, 0, 0};
    if (col < N_HEADS)
        qf = *(const bf16x8*)(Qb + (size_t)dst * D_MODEL + col * 32 + kq * 8);
    const bf16x8 zf = (bf16x8){0, 0, 0, 0, 0, 0, 0, 0};
    const float inv_scale = 0.17677669529663687f;   // 1/sqrt(32)

    // PV-lane config: head h, dims 4L..4L+3
    int h = L >> 3;
    const unsigned short* vbase = Vb + 4 * L;

    // running softmax state (per PV lane; redundant across the 8 lanes of h)
    float m = -1e30f, l = 0.f;
    f32x4 acc = (f32x4){0.f, 0.f, 0.f, 0.f};

    bf16x8 KA[8], KBx[8];
    LOAD_K(KA, 0);
    for (int t = 0; t < nt; t += 2) {
        TILE_BODY(KA, KBx, t);
        if (t + 1 < nt) TILE_BODY(KBx, KA, t + 1);
    }

    float rl = 1.f / l;
    ushort4 o;
    o.x = f2bf(acc[0] * rl); o.y = f2bf(acc[1] * rl);
    o.z = f2bf(acc[2] * rl); o.w = f2bf(acc[3] * rl);
    *(ushort4*)(Ob + (size_t)dst * D_MODEL + 4 * L) = o;
}

// ---------------------------------------------------------------------------
// Fused output GEMM + residual + bias + LayerNorm.
// BM=32, BN=256 (full row), BK=64 -> 128 blocks (R5-measured best).
// ---------------------------------------------------------------------------
struct SMemO {
    union {
        struct { short A[32][72]; short B[256][72]; } st;
        float c[32][260];
    };
};

__global__ __launch_bounds__(256) void gemm_o_ln_kernel(
        const unsigned short* __restrict__ Ob, const unsigned short* __restrict__ Wob,
        const float* __restrict__ x, const float* __restrict__ bo,
        const float* __restrict__ gamma, const float* __restrict__ beta,
        float* __restrict__ out) {
    __shared__ SMemO sm;
    int by = blockIdx.x;
    int t = threadIdx.x;
    int wave = t >> 6, lane = t & 63;
    int rt = wave >> 1, cq = wave & 1;
    int lr = t >> 3;
    int lk = (t & 7) << 3;

    const unsigned short* Abase = Ob + ((size_t)(by * 32 + lr)) * D_MODEL + lk;
    int fm = lane & 15;
    int fk = (lane >> 4) << 3;

    f32x4 acc[8];
#pragma unroll
    for (int ct = 0; ct < 8; ++ct) acc[ct] = (f32x4){0.f, 0.f, 0.f, 0.f};

    for (int k0 = 0; k0 < D_MODEL; k0 += 64) {
        *(uint4*)&sm.st.A[lr][lk] = *(const uint4*)(Abase + k0);
#pragma unroll
        for (int j = 0; j < 8; ++j)
            *(uint4*)&sm.st.B[lr + 32 * j][lk] =
                *(const uint4*)(Wob + ((size_t)(lr + 32 * j)) * D_MODEL + k0 + lk);
        __syncthreads();
#pragma unroll
        for (int ks = 0; ks < 64; ks += 32) {
            bf16x8 af = *(const bf16x8*)&sm.st.A[rt * 16 + fm][ks + fk];
#pragma unroll
            for (int ct = 0; ct < 8; ++ct) {
                bf16x8 bf = *(const bf16x8*)&sm.st.B[cq * 128 + ct * 16 + fm][ks + fk];
                acc[ct] = __builtin_amdgcn_mfma_f32_16x16x32_bf16(af, bf, acc[ct], 0, 0, 0);
            }
        }
        __syncthreads();
    }

    int rr0 = rt * 16 + ((lane >> 4) << 2);
#pragma unroll
    for (int ct = 0; ct < 8; ++ct)
#pragma unroll
        for (int q = 0; q < 4; ++q)
            sm.c[rr0 + q][cq * 128 + ct * 16 + (lane & 15)] = acc[ct][q];
    __syncthreads();

    float4 bo4 = *(const float4*)(bo + lane * 4);
    float4 g4  = *(const float4*)(gamma + lane * 4);
    float4 be4 = *(const float4*)(beta + lane * 4);
#pragma unroll
    for (int rr = 0; rr < 8; ++rr) {
        int r = wave * 8 + rr;
        int grow = by * 32 + r;
        float4 p = *(const float4*)&sm.c[r][lane * 4];
        float4 xv = *(const float4*)(x + (size_t)grow * D_MODEL + lane * 4);
        float hx = p.x + xv.x + bo4.x;
        float hy = p.y + xv.y + bo4.y;
        float hz = p.z + xv.z + bo4.z;
        float hw = p.w + xv.w + bo4.w;
        float s  = (hx + hy) + (hz + hw);
        float s2 = (hx * hx + hy * hy) + (hz * hz + hw * hw);
#pragma unroll
        for (int o = 32; o; o >>= 1) {
            s  += __shfl_xor(s, o, 64);
            s2 += __shfl_xor(s2, o, 64);
        }
        float mu = s * (1.f / 256.f);
        float var = s2 * (1.f / 256.f) - mu * mu;
        float rstd = rsqrtf(var + 1e-5f);
        float4 o4;
        o4.x = (hx - mu) * rstd * g4.x + be4.x;
        o4.y = (hy - mu) * rstd * g4.y + be4.y;
        o4.z = (hz - mu) * rstd * g4.z + be4.z;
        o4.w = (hw - mu) * rstd * g4.w + be4.w;
        *(float4*)(out + (size_t)grow * D_MODEL + lane * 4) = o4;
    }
}

// ---------------------------------------------------------------------------
extern "C" void kernel_launch(void* const* d_in, const int* in_sizes, int n_in,
                              void* d_out, int out_size, void* d_ws, size_t ws_size,
                              hipStream_t stream) {
    const float* x     = (const float*)d_in[0];
    const int*   ei    = (const int*)  d_in[1];
    const float* Wq    = (const float*)d_in[2];
    const float* Wk    = (const float*)d_in[3];
    const float* Wv    = (const float*)d_in[4];
    const float* Wo    = (const float*)d_in[5];
    const float* bo    = (const float*)d_in[6];
    const float* gamma = (const float*)d_in[7];
    const float* beta  = (const float*)d_in[8];
    float* out = (float*)d_out;

    int n = in_sizes[0] / D_MODEL;   // 4096
    int E = in_sizes[1] / 2;         // 131072

    char* ws = (char*)d_ws;
    size_t off = 0;
    unsigned long long* mask = (unsigned long long*)(ws + off);
    off += (size_t)n * (n >> 6) * sizeof(unsigned long long);          // 2 MiB
    unsigned short* xb  = (unsigned short*)(ws + off); off += (size_t)n * D_MODEL * 2;
    unsigned short* Wqb = (unsigned short*)(ws + off); off += D_MODEL * D_MODEL * 2;
    unsigned short* Wkb = (unsigned short*)(ws + off); off += D_MODEL * D_MODEL * 2;
    unsigned short* Wvb = (unsigned short*)(ws + off); off += D_MODEL * D_MODEL * 2;
    unsigned short* Wob = (unsigned short*)(ws + off); off += D_MODEL * D_MODEL * 2;
    unsigned short* Qb  = (unsigned short*)(ws + off); off += (size_t)n * D_MODEL * 2;
    unsigned short* Kb  = (unsigned short*)(ws + off); off += (size_t)n * D_MODEL * 2;
    unsigned short* Vb  = (unsigned short*)(ws + off); off += (size_t)n * D_MODEL * 2;
    unsigned short* Ob  = (unsigned short*)(ws + off); off += (size_t)n * D_MODEL * 2;

    // 1) prep: converts + mask init (diag)
    prep_kernel<<<1280, 256, 0, stream>>>(x, Wq, Wk, Wv, Wo,
                                          xb, Wqb, Wkb, Wvb, Wob, mask, n);

    // 2) fused QKV GEMM + edge scatter
    int edge_blocks = (E + 255) / 256;       // 512
    qkv_edges_kernel<<<NGEMM + edge_blocks, 256, 0, stream>>>(
        xb, Wqb, Wkb, Wvb, Qb, Kb, Vb, ei, mask, E, n);

    // 3) sparse attention: one wave per dst, single-pass online softmax
    attn_kernel<<<n, 64, 0, stream>>>(Qb, Kb, Vb, mask, Ob, n);

    // 4) output GEMM + residual + LayerNorm
    gemm_o_ln_kernel<<<n / 32, 256, 0, stream>>>(Ob, Wob, x, bo, gamma, beta, out);
}